// Round 3
// baseline (120.713 us; speedup 1.0000x reference)
//
#include <hip/hip_runtime.h>
#include <cmath>

constexpr int Bn = 4, Cn = 128, Hn = 64, Wn = 64, Kn = 7, NHn = 8, DHn = 16, PADn = 3;
constexpr int HWn = Hn * Wn;              // 4096 pixels per batch
constexpr int TS = 16;                    // pixel tile edge
constexpr size_t QPLANE = (size_t)Bn * NHn * HWn * DHn;   // 2,097,152 elems per q plane

// fused qkv geometry
constexpr int SP   = 64;                  // pixel strip per block
constexpr int XROW = 136;                 // xT LDS row stride in u16 (128 + 8 pad)

// sasa LDS geometry
constexpr int HR = 22;                    // halo rows (16 + 6)
constexpr int HC = 24;                    // halo cols staged (22 live + 2, OOB->bias fill)
constexpr int KP = 24;                    // ksm pixel stride in u16: 16 data + 8 pad (48 B)
constexpr int VW = 15;                    // vsm u32-word stride per [hh][d] row (15 = conflict-free)

typedef float f32x4 __attribute__((ext_vector_type(4)));
typedef short short8 __attribute__((ext_vector_type(8)));
typedef unsigned int u32x4 __attribute__((ext_vector_type(4)));
typedef unsigned short u16x4 __attribute__((ext_vector_type(4)));
typedef unsigned short u16x8 __attribute__((ext_vector_type(8)));

__device__ __forceinline__ unsigned short f32_to_bf16_rne(float f) {
  unsigned u = __float_as_uint(f);
  unsigned r = u + 0x7fffu + ((u >> 16) & 1u);
  return (unsigned short)(r >> 16);
}
__device__ __forceinline__ float bf16_to_f32(unsigned short h) {
  return __uint_as_float(((unsigned)h) << 16);
}
// pack two f32 into one u32 of 2x bf16 (truncation; weights only)
__device__ __forceinline__ unsigned pk_bf16(float lo, float hi) {
  return (__float_as_uint(lo) >> 16) | (__float_as_uint(hi) & 0xffff0000u);
}
__device__ __forceinline__ f32x4 max4(f32x4 a, f32x4 b) {
  a[0] = fmaxf(a[0], b[0]); a[1] = fmaxf(a[1], b[1]);
  a[2] = fmaxf(a[2], b[2]); a[3] = fmaxf(a[3], b[3]);
  return a;
}

union UVcast { u32x4 u; short8 s; };

// ---------------------------------------------------------------------------
// Fused prep + qkv projection.  One block = (batch, 64-pixel strip), 512 thr.
//  Phase 1: whole 128ch x 64px fp32 x-tile -> registers (4 f32x4/thread).
//  Phase 2: regs -> smf fp32 (4-chunk buffered, ONE barrier) -> transpose +
//           convert to bf16 hi/lo LDS planes on ALL 512 threads (2 tasks each),
//           row-XOR-swizzled (csw = c ^ ((px&7)<<3)), ONE barrier.
//  Phase 3: waves 0..5 each compute one 64x64 tile (mat=wave>>1, half=wave&1)
//           via split-bf16 MFMA; W rows loaded fp32 from global (L2-resident)
//           and hi/lo-split in-register.
// Outputs: q -> bf16 hi/lo planes [b][n][p][d]; k,v -> bf16 [b][n][p][d].
// grid (64, 1, 4), block 512.  LDS 68.1 KB.
// ---------------------------------------------------------------------------
__global__ __launch_bounds__(512)
void qkv_fused(const float* __restrict__ x,
               const float* __restrict__ wq, const float* __restrict__ wk,
               const float* __restrict__ wv,
               const float* __restrict__ bq_, const float* __restrict__ bk_,
               const float* __restrict__ bv_,
               unsigned short* __restrict__ qo, unsigned short* __restrict__ kbf,
               unsigned short* __restrict__ vbf)
{
  __shared__ float smf[4][32][SP + 1];                      // 33.3 KB
  __shared__ __align__(16) unsigned short xthi[SP * XROW];  // 17.4 KB
  __shared__ __align__(16) unsigned short xtlo[SP * XROW];  // 17.4 KB

  const int b   = blockIdx.z;
  const int p0  = blockIdx.x * SP;
  const int tid = threadIdx.x;
  const float* xb = x + (size_t)b * Cn * HWn;

  // ---- phase 1: front-load the whole x tile (channel = 32*k + tid>>4)
  f32x4 xr0, xr1, xr2, xr3;
  {
    const int c  = tid >> 4;
    const int p4 = (tid & 15) * 4;
    const float* bp = xb + (size_t)c * HWn + p0 + p4;
    xr0 = *reinterpret_cast<const f32x4*>(bp);
    xr1 = *reinterpret_cast<const f32x4*>(bp + (size_t)32 * HWn);
    xr2 = *reinterpret_cast<const f32x4*>(bp + (size_t)64 * HWn);
    xr3 = *reinterpret_cast<const f32x4*>(bp + (size_t)96 * HWn);
  }

  // ---- phase 2a: all four 32-ch chunks into smf, single barrier
  {
    const int cl = tid >> 4;
    const int p4 = (tid & 15) * 4;
#pragma unroll
    for (int j = 0; j < 4; ++j) smf[0][cl][p4 + j] = xr0[j];
#pragma unroll
    for (int j = 0; j < 4; ++j) smf[1][cl][p4 + j] = xr1[j];
#pragma unroll
    for (int j = 0; j < 4; ++j) smf[2][cl][p4 + j] = xr2[j];
#pragma unroll
    for (int j = 0; j < 4; ++j) smf[3][cl][p4 + j] = xr3[j];
  }
  __syncthreads();

  // ---- phase 2b: transpose+convert on all 512 threads (1024 tasks)
#pragma unroll
  for (int rep = 0; rep < 2; ++rep) {
    const int task = rep * 512 + tid;
    const int cc   = task >> 8;          // chunk 0..3
    const int t2   = task & 255;
    const int pl   = t2 >> 2;            // pixel 0..63
    const int c0l  = (t2 & 3) * 8;       // channel group within chunk
    u32x4 hw, lw;
#pragma unroll
    for (int j = 0; j < 4; ++j) {
      const float v0 = smf[cc][c0l + 2 * j][pl];
      const float v1 = smf[cc][c0l + 2 * j + 1][pl];
      const unsigned short h0 = f32_to_bf16_rne(v0);
      const unsigned short h1 = f32_to_bf16_rne(v1);
      const unsigned short l0 = f32_to_bf16_rne(v0 - bf16_to_f32(h0));
      const unsigned short l1 = f32_to_bf16_rne(v1 - bf16_to_f32(h1));
      hw[j] = h0 | ((unsigned)h1 << 16);
      lw[j] = l0 | ((unsigned)l1 << 16);
    }
    const int csw = (cc * 32 + c0l) ^ ((pl & 7) << 3);   // XOR-swizzle bits 3..5
    *reinterpret_cast<u32x4*>(xthi + pl * XROW + csw) = hw;
    *reinterpret_cast<u32x4*>(xtlo + pl * XROW + csw) = lw;
  }
  __syncthreads();

  // ---- phase 3: MFMA (waves 0..5), one 64x64 tile per wave
  const int wave = tid >> 6;
  if (wave >= 6) return;
  const int lane = tid & 63;
  const int r    = lane & 15;
  const int quad = lane >> 4;
  const int mat  = wave >> 1;              // 0=q,1=k,2=v
  const int half = wave & 1;
  const int mbase = half * 64;
  const float* Wsel = (mat == 0) ? wq : (mat == 1) ? wk : wv;
  const float* bias = (mat == 0) ? bq_ : (mat == 1) ? bk_ : bv_;

  f32x4 acc[4][4] = {};

#pragma unroll
  for (int ks = 0; ks < 4; ++ks) {
    const int kk = ks * 32 + quad * 8;
    short8 Ah[4], Al[4], Bh[4], Bl[4];
#pragma unroll
    for (int mt = 0; mt < 4; ++mt) {
      const float* wp = Wsel + (size_t)(mbase + mt * 16 + r) * Cn + kk;
      const f32x4 wa = *reinterpret_cast<const f32x4*>(wp);
      const f32x4 wb = *reinterpret_cast<const f32x4*>(wp + 4);
      short8 ah, al;
#pragma unroll
      for (int j = 0; j < 4; ++j) {
        const unsigned short h = f32_to_bf16_rne(wa[j]);
        ah[j] = (short)h;
        al[j] = (short)f32_to_bf16_rne(wa[j] - bf16_to_f32(h));
      }
#pragma unroll
      for (int j = 0; j < 4; ++j) {
        const unsigned short h = f32_to_bf16_rne(wb[j]);
        ah[4 + j] = (short)h;
        al[4 + j] = (short)f32_to_bf16_rne(wb[j] - bf16_to_f32(h));
      }
      Ah[mt] = ah; Al[mt] = al;
    }
#pragma unroll
    for (int nt = 0; nt < 4; ++nt) {
      const int px  = nt * 16 + r;
      const int csw = kk ^ ((px & 7) << 3);
      Bh[nt] = *reinterpret_cast<const short8*>(xthi + px * XROW + csw);
      Bl[nt] = *reinterpret_cast<const short8*>(xtlo + px * XROW + csw);
    }
#pragma unroll
    for (int mt = 0; mt < 4; ++mt)
#pragma unroll
      for (int nt = 0; nt < 4; ++nt) {
        acc[mt][nt] = __builtin_amdgcn_mfma_f32_16x16x32_bf16(Ah[mt], Bh[nt], acc[mt][nt], 0, 0, 0);
        acc[mt][nt] = __builtin_amdgcn_mfma_f32_16x16x32_bf16(Ah[mt], Bl[nt], acc[mt][nt], 0, 0, 0);
        acc[mt][nt] = __builtin_amdgcn_mfma_f32_16x16x32_bf16(Al[mt], Bh[nt], acc[mt][nt], 0, 0, 0);
      }
  }

  // ---- epilogue: lane holds pixel p0+nt*16+r, head n=half*4+mt, d=quad*4+reg
#pragma unroll
  for (int mt = 0; mt < 4; ++mt) {
    const int n = half * 4 + mt;
    const f32x4 b4 = *reinterpret_cast<const f32x4*>(bias + mbase + mt * 16 + quad * 4);
#pragma unroll
    for (int nt = 0; nt < 4; ++nt) {
      const int p = p0 + nt * 16 + r;
      const size_t off = ((size_t)((b * NHn + n) * HWn + p)) * DHn + quad * 4;
      f32x4 val = acc[mt][nt] + b4;
      if (mat == 0) {
        u16x4 hi4, lo4;
#pragma unroll
        for (int j = 0; j < 4; ++j) {
          const unsigned short hb = f32_to_bf16_rne(val[j]);
          hi4[j] = hb;
          lo4[j] = f32_to_bf16_rne(val[j] - bf16_to_f32(hb));
        }
        *reinterpret_cast<u16x4*>(qo + off)          = hi4;
        *reinterpret_cast<u16x4*>(qo + QPLANE + off) = lo4;
      } else {
        unsigned short* y = (mat == 1) ? kbf : vbf;
        u16x4 pkv;
        pkv[0] = f32_to_bf16_rne(val[0]); pkv[1] = f32_to_bf16_rne(val[1]);
        pkv[2] = f32_to_bf16_rne(val[2]); pkv[3] = f32_to_bf16_rne(val[3]);
        *reinterpret_cast<u16x4*>(y + off) = pkv;
      }
    }
  }
}

// ---------------------------------------------------------------------------
// Kernel 2: SASA attention via MFMA.  XCD-aware block remap: each XCD owns
// 4 (b,head) z-planes, 16 tiles each temporally contiguous -> k/v/q planes
// fetched once per XCD L2, halo overlap becomes L2 hits.
// grid (4, 4, 32) [remapped internally], block 256.  LDS 46.4 KB.
// ---------------------------------------------------------------------------
__global__ __launch_bounds__(256)
void sasa_attn(const unsigned short* __restrict__ qhl,
               const unsigned short* __restrict__ kbf,
               const unsigned short* __restrict__ vbf,
               const float* __restrict__ bk_, const float* __restrict__ bv_,
               const float* __restrict__ pos_h, const float* __restrict__ pos_w,
               float* __restrict__ out)
{
  __shared__ __align__(16) unsigned short ksm[HR * HC * KP];   // 25,344 B
  __shared__ __align__(16) unsigned       vsm[HR * DHn * VW];  // 21,120 B

  // ---- XCD-aware remap (bijective: 512 blocks, 8 XCDs, id%8 round-robin)
  const int flat = blockIdx.z * 16 + blockIdx.y * 4 + blockIdx.x;
  const int xcd  = flat & 7;
  const int slot = flat >> 3;              // 0..63
  const int z    = xcd * 4 + (slot >> 4);  // 4 z-planes per XCD
  const int tile = slot & 15;              // tiles contiguous within z

  const int b  = z >> 3;
  const int n  = z & 7;
  const int h0 = (tile >> 2) * TS;
  const int w0 = (tile & 3) * TS;
  const int tid  = threadIdx.x;
  const int lane = tid & 63;
  const int wv   = tid >> 6;
  const int r    = lane & 15;
  const int quad = lane >> 4;
  const int cbase = n * DHn;

  const unsigned short* kb = kbf + ((size_t)(b * NHn + n) * HWn) * DHn;
  const unsigned short* vb = vbf + ((size_t)(b * NHn + n) * HWn) * DHn;
  const size_t qbase = ((size_t)(b * NHn + n) * HWn) * DHn;
  const unsigned short* qhp = qhl + qbase;
  const unsigned short* qlp = qhl + QPLANE + qbase;

  // ---- hoist q loads (4 rows) so HBM latency hides under LDS staging
  const unsigned short* qsel = (quad < 2) ? qhp : qlp;
  short8 qf[4];
#pragma unroll
  for (int hl = 0; hl < 4; ++hl) {
    const int pix = (h0 + wv * 4 + hl) * Wn + (w0 + r);
    qf[hl] = *reinterpret_cast<const short8*>(qsel + (size_t)pix * DHn + (quad & 1) * 8);
  }

  // bias halves as packed bf16 (for OOB halo pixels)
  u16x8 kb0, kb1, vb0, vb1;
#pragma unroll
  for (int j = 0; j < 8; ++j) {
    kb0[j] = f32_to_bf16_rne(bk_[cbase + j]);
    kb1[j] = f32_to_bf16_rne(bk_[cbase + 8 + j]);
    vb0[j] = f32_to_bf16_rne(bv_[cbase + j]);
    vb1[j] = f32_to_bf16_rne(bv_[cbase + 8 + j]);
  }

  // ---- stage K halo: 22x24 pixels x 2 halves (16 B each), [hh][ww][16+8pad]
  for (int c = tid; c < HR * HC * 2; c += 256) {
    const int pix  = c >> 1;
    const int half = c & 1;
    const int hh = pix / HC;
    const int ww = pix - hh * HC;
    const int gh = h0 + hh - PADn;
    const int gw = w0 + ww - PADn;
    const bool inb = (gh >= 0) && (gh < Hn) && (gw >= 0) && (gw < Wn);
    u16x8 kd;
    if (inb) kd = *reinterpret_cast<const u16x8*>(kb + ((size_t)(gh * Wn + gw)) * DHn + half * 8);
    else     kd = half ? kb1 : kb0;
    *reinterpret_cast<u16x8*>(ksm + pix * KP + half * 8) = kd;
  }

  // ---- stage V halo TRANSPOSED: vsm[hh][d][ww-pair] as u32 (lo=even ww)
  for (int pp = tid; pp < HR * (HC / 2); pp += 256) {
    const int hh = pp / (HC / 2);
    const int wp = pp - hh * (HC / 2);
    const int gh = h0 + hh - PADn;
    u16x8 a0, a1, c0, c1;
    {
      const int gw = w0 + 2 * wp - PADn;
      const bool inb = (gh >= 0) && (gh < Hn) && (gw >= 0) && (gw < Wn);
      if (inb) {
        const size_t src = ((size_t)(gh * Wn + gw)) * DHn;
        a0 = *reinterpret_cast<const u16x8*>(vb + src);
        a1 = *reinterpret_cast<const u16x8*>(vb + src + 8);
      } else { a0 = vb0; a1 = vb1; }
    }
    {
      const int gw = w0 + 2 * wp + 1 - PADn;
      const bool inb = (gh >= 0) && (gh < Hn) && (gw >= 0) && (gw < Wn);
      if (inb) {
        const size_t src = ((size_t)(gh * Wn + gw)) * DHn;
        c0 = *reinterpret_cast<const u16x8*>(vb + src);
        c1 = *reinterpret_cast<const u16x8*>(vb + src + 8);
      } else { c0 = vb0; c1 = vb1; }
    }
    unsigned* dst = vsm + (hh * DHn) * VW + wp;
#pragma unroll
    for (int d = 0; d < 8; ++d)
      dst[d * VW] = (unsigned)(unsigned short)a0[d] | ((unsigned)(unsigned short)c0[d] << 16);
#pragma unroll
    for (int d = 0; d < 8; ++d)
      dst[(8 + d) * VW] = (unsigned)(unsigned short)a1[d] | ((unsigned)(unsigned short)c1[d] << 16);
  }

  // ---- per-lane static pos_w + band-validity masks
  float ph[7];
#pragma unroll
  for (int i = 0; i < 7; ++i) ph[i] = pos_h[n * Kn + i];
  f32x4 pw4[2];
#pragma unroll
  for (int win = 0; win < 2; ++win) {
#pragma unroll
    for (int reg = 0; reg < 4; ++reg) {
      const int ww = win * 8 + 4 * quad + reg;
      const int j  = ww - r;
      const bool valid = (j >= 0) && (j < 7) && (win == 0 || ww >= 16);
      const int jc = j < 0 ? 0 : (j > 6 ? 6 : j);
      const float pv = pos_w[n * Kn + jc];
      pw4[win][reg] = valid ? pv : -1e30f;
    }
  }

  __syncthreads();

  const f32x4 zero4 = {};
  for (int hl = 0; hl < 4; ++hl) {
    const int h = wv * 4 + hl;

    // ---- logits: 14 MFMAs (7 i x 2 windows)
    f32x4 L[14];
#pragma unroll
    for (int i = 0; i < 7; ++i) {
#pragma unroll
      for (int win = 0; win < 2; ++win) {
        const short8 kf = *reinterpret_cast<const short8*>(
            ksm + ((h + i) * HC + win * 8 + r) * KP + (quad & 1) * 8);
        f32x4 d = __builtin_amdgcn_mfma_f32_16x16x32_bf16(kf, qf[hl], zero4, 0, 0, 0);
        d = d + pw4[win];
        d = d + (f32x4)ph[i];
        L[i * 2 + win] = d;
      }
    }

    // ---- softmax over this pixel's 49 valid slots
    f32x4 M4 = L[0];
#pragma unroll
    for (int t = 1; t < 14; ++t) M4 = max4(M4, L[t]);
    float m = fmaxf(fmaxf(M4[0], M4[1]), fmaxf(M4[2], M4[3]));
    m = fmaxf(m, __shfl_xor(m, 16, 64));
    m = fmaxf(m, __shfl_xor(m, 32, 64));

    f32x4 S4 = {};
#pragma unroll
    for (int t = 0; t < 14; ++t) {
      f32x4 e;
      e[0] = __expf(L[t][0] - m);
      e[1] = __expf(L[t][1] - m);
      e[2] = __expf(L[t][2] - m);
      e[3] = __expf(L[t][3] - m);
      L[t] = e;
      S4 += e;
    }
    float s = (S4[0] + S4[1]) + (S4[2] + S4[3]);
    s += __shfl_xor(s, 16, 64);
    s += __shfl_xor(s, 32, 64);
    const float inv = 1.0f / s;

    // ---- PV: 7 MFMAs, weights in-lane (D-fragment == A-fragment layout)
    f32x4 oA = {}, oB = {};
#pragma unroll
    for (int i = 0; i < 7; ++i) {
      const f32x4 e0 = L[2 * i]     * (f32x4)inv;
      const f32x4 e1 = L[2 * i + 1] * (f32x4)inv;
      UVcast A;
      A.u[0] = pk_bf16(e0[0], e0[1]);
      A.u[1] = pk_bf16(e0[2], e0[3]);
      A.u[2] = pk_bf16(e1[0], e1[1]);
      A.u[3] = pk_bf16(e1[2], e1[3]);

      const unsigned* vp = vsm + ((h + i) * DHn + r) * VW + 2 * quad;
      const uint2 v0 = *reinterpret_cast<const uint2*>(vp);
      const uint2 v1 = *reinterpret_cast<const uint2*>(vp + 4);
      UVcast Bv;
      Bv.u[0] = v0.x; Bv.u[1] = v0.y; Bv.u[2] = v1.x; Bv.u[3] = v1.y;

      f32x4& acc = (i & 1) ? oB : oA;
      acc = __builtin_amdgcn_mfma_f32_16x16x32_bf16(A.s, Bv.s, acc, 0, 0, 0);
    }
    const f32x4 O = oA + oB;

    // ---- store: D[row=w=4q+reg][col=d=r] -> f32x4 contiguous in w
    float* op = out + ((size_t)(b * Cn + cbase + r)) * HWn + (h0 + h) * Wn + w0 + 4 * quad;
    *reinterpret_cast<f32x4*>(op) = O;
  }
}

// ---------------------------------------------------------------------------
extern "C" void kernel_launch(void* const* d_in, const int* in_sizes, int n_in,
                              void* d_out, int out_size, void* d_ws, size_t ws_size,
                              hipStream_t stream) {
  const float* x     = (const float*)d_in[0];
  const float* wq    = (const float*)d_in[1];
  const float* bq    = (const float*)d_in[2];
  const float* wk    = (const float*)d_in[3];
  const float* bk    = (const float*)d_in[4];
  const float* wv    = (const float*)d_in[5];
  const float* bv    = (const float*)d_in[6];
  const float* pos_h = (const float*)d_in[7];
  const float* pos_w = (const float*)d_in[8];
  float* out = (float*)d_out;

  const size_t tensor_elems = (size_t)Bn * Cn * HWn;          // 2,097,152
  unsigned short* qhl = (unsigned short*)d_ws;                // 8 MiB (hi+lo planes)
  unsigned short* kbf = qhl + 2 * tensor_elems;               // 4 MiB
  unsigned short* vbf = kbf + tensor_elems;                   // 4 MiB

  dim3 gq(HWn / SP, 1, Bn);              // (64, 1, 4)
  qkv_fused<<<gq, 512, 0, stream>>>(x, wq, wk, wv, bq, bk, bv, qhl, kbf, vbf);

  dim3 g2(Wn / TS, Hn / TS, Bn * NHn);   // (4, 4, 32)
  sasa_attn<<<g2, 256, 0, stream>>>(qhl, kbf, vbf, bk, bv, pos_h, pos_w, out);
}

// Round 4
// 106.613 us; speedup vs baseline: 1.1323x; 1.1323x over previous
//
#include <hip/hip_runtime.h>
#include <cmath>

constexpr int Bn = 4, Cn = 128, Hn = 64, Wn = 64, Kn = 7, NHn = 8, DHn = 16, PADn = 3;
constexpr int HWn = Hn * Wn;              // 4096 pixels per batch
constexpr int TS = 16;                    // pixel tile edge
constexpr size_t QPLANE = (size_t)Bn * NHn * HWn * DHn;   // 2,097,152 elems per q plane

// fused qkv geometry
constexpr int SP   = 64;                  // pixel strip per block
constexpr int XROW = 136;                 // xT LDS row stride in u16 (128 + 8 pad)

// sasa LDS geometry
constexpr int HR = 22;                    // halo rows (16 + 6)
constexpr int HC = 24;                    // halo cols staged (22 live + 2, OOB->bias fill)
constexpr int KP = 24;                    // ksm pixel stride in u16: 16 data + 8 pad (48 B)
constexpr int VW = 14;                    // vsm u32-word stride per [hh][d] row: 12 data + 2 pad
                                          // (2-way bank alias on uint2 reads = free on CDNA4)

typedef float f32x4 __attribute__((ext_vector_type(4)));
typedef short short8 __attribute__((ext_vector_type(8)));
typedef unsigned int u32x4 __attribute__((ext_vector_type(4)));
typedef unsigned short u16x4 __attribute__((ext_vector_type(4)));
typedef unsigned short u16x8 __attribute__((ext_vector_type(8)));

__device__ __forceinline__ unsigned short f32_to_bf16_rne(float f) {
  unsigned u = __float_as_uint(f);
  unsigned r = u + 0x7fffu + ((u >> 16) & 1u);
  return (unsigned short)(r >> 16);
}
__device__ __forceinline__ float bf16_to_f32(unsigned short h) {
  return __uint_as_float(((unsigned)h) << 16);
}
// pack two f32 into one u32 of 2x bf16 (truncation; weights only)
__device__ __forceinline__ unsigned pk_bf16(float lo, float hi) {
  return (__float_as_uint(lo) >> 16) | (__float_as_uint(hi) & 0xffff0000u);
}
__device__ __forceinline__ f32x4 max4(f32x4 a, f32x4 b) {
  a[0] = fmaxf(a[0], b[0]); a[1] = fmaxf(a[1], b[1]);
  a[2] = fmaxf(a[2], b[2]); a[3] = fmaxf(a[3], b[3]);
  return a;
}

union UVcast { u32x4 u; short8 s; };

// ---------------------------------------------------------------------------
// Fused prep + qkv projection.  One block = (batch, 64-pixel strip), 512 thr.
//  Phase 1: whole 128ch x 64px fp32 x-tile -> registers (4 f32x4/thread).
//  Phase 2 (x4 chunks of 32 ch): regs -> smf fp32 -> transpose+convert to
//           bf16 hi/lo LDS planes, row-XOR-swizzled (csw = c ^ ((px&7)<<3))
//           to break the 272B-stride bank conflict on fragment ds_read_b128.
//  Phase 3: waves 0..5 each compute one 64x64 tile (mat=wave>>1, half=wave&1)
//           via split-bf16 MFMA; A (=W rows) loaded fp32 from global
//           (192 KB total, L2-resident) and hi/lo-split in-register.
// Outputs: q -> bf16 hi/lo planes [b][n][p][d]; k,v -> bf16 [b][n][p][d].
// grid (64, 1, 4), block 512.  LDS 43.3 KB.
// ---------------------------------------------------------------------------
__global__ __launch_bounds__(512)
void qkv_fused(const float* __restrict__ x,
               const float* __restrict__ wq, const float* __restrict__ wk,
               const float* __restrict__ wv,
               const float* __restrict__ bq_, const float* __restrict__ bk_,
               const float* __restrict__ bv_,
               unsigned short* __restrict__ qo, unsigned short* __restrict__ kbf,
               unsigned short* __restrict__ vbf)
{
  __shared__ float smf[32][SP + 1];                         // 8.45 KB
  __shared__ __align__(16) unsigned short xthi[SP * XROW];  // 17.4 KB
  __shared__ __align__(16) unsigned short xtlo[SP * XROW];  // 17.4 KB

  const int b   = blockIdx.z;
  const int p0  = blockIdx.x * SP;
  const int tid = threadIdx.x;
  const float* xb = x + (size_t)b * Cn * HWn;

  // ---- phase 1: front-load the whole x tile (channel = 32*k + tid>>4)
  f32x4 xr0, xr1, xr2, xr3;
  {
    const int c  = tid >> 4;
    const int p4 = (tid & 15) * 4;
    const float* bp = xb + (size_t)c * HWn + p0 + p4;
    xr0 = *reinterpret_cast<const f32x4*>(bp);
    xr1 = *reinterpret_cast<const f32x4*>(bp + (size_t)32 * HWn);
    xr2 = *reinterpret_cast<const f32x4*>(bp + (size_t)64 * HWn);
    xr3 = *reinterpret_cast<const f32x4*>(bp + (size_t)96 * HWn);
  }

  // ---- phase 2: 4 chunks of 32 channels
#pragma unroll
  for (int cc = 0; cc < 4; ++cc) {
    const f32x4 v = (cc == 0) ? xr0 : (cc == 1) ? xr1 : (cc == 2) ? xr2 : xr3;
    const int cl = tid >> 4;
    const int p4 = (tid & 15) * 4;
    smf[cl][p4 + 0] = v[0]; smf[cl][p4 + 1] = v[1];
    smf[cl][p4 + 2] = v[2]; smf[cl][p4 + 3] = v[3];
    __syncthreads();
    if (tid < 256) {
      const int pl  = tid >> 2;            // pixel 0..63
      const int c0l = (tid & 3) * 8;       // channel group within chunk
      u32x4 hw, lw;
#pragma unroll
      for (int j = 0; j < 4; ++j) {
        const float v0 = smf[c0l + 2 * j][pl];
        const float v1 = smf[c0l + 2 * j + 1][pl];
        const unsigned short h0 = f32_to_bf16_rne(v0);
        const unsigned short h1 = f32_to_bf16_rne(v1);
        const unsigned short l0 = f32_to_bf16_rne(v0 - bf16_to_f32(h0));
        const unsigned short l1 = f32_to_bf16_rne(v1 - bf16_to_f32(h1));
        hw[j] = h0 | ((unsigned)h1 << 16);
        lw[j] = l0 | ((unsigned)l1 << 16);
      }
      const int csw = (cc * 32 + c0l) ^ ((pl & 7) << 3);   // XOR-swizzle bits 3..5
      *reinterpret_cast<u32x4*>(xthi + pl * XROW + csw) = hw;
      *reinterpret_cast<u32x4*>(xtlo + pl * XROW + csw) = lw;
    }
    __syncthreads();
  }

  // ---- phase 3: MFMA (waves 0..5), one 64x64 tile per wave
  const int wave = tid >> 6;
  if (wave >= 6) return;
  const int lane = tid & 63;
  const int r    = lane & 15;
  const int quad = lane >> 4;
  const int mat  = wave >> 1;              // 0=q,1=k,2=v
  const int half = wave & 1;
  const int mbase = half * 64;
  const float* Wsel = (mat == 0) ? wq : (mat == 1) ? wk : wv;
  const float* bias = (mat == 0) ? bq_ : (mat == 1) ? bk_ : bv_;

  f32x4 acc[4][4] = {};

#pragma unroll
  for (int ks = 0; ks < 4; ++ks) {
    const int kk = ks * 32 + quad * 8;
    short8 Ah[4], Al[4], Bh[4], Bl[4];
#pragma unroll
    for (int mt = 0; mt < 4; ++mt) {
      const float* wp = Wsel + (size_t)(mbase + mt * 16 + r) * Cn + kk;
      const f32x4 wa = *reinterpret_cast<const f32x4*>(wp);
      const f32x4 wb = *reinterpret_cast<const f32x4*>(wp + 4);
      short8 ah, al;
#pragma unroll
      for (int j = 0; j < 4; ++j) {
        const unsigned short h = f32_to_bf16_rne(wa[j]);
        ah[j] = (short)h;
        al[j] = (short)f32_to_bf16_rne(wa[j] - bf16_to_f32(h));
      }
#pragma unroll
      for (int j = 0; j < 4; ++j) {
        const unsigned short h = f32_to_bf16_rne(wb[j]);
        ah[4 + j] = (short)h;
        al[4 + j] = (short)f32_to_bf16_rne(wb[j] - bf16_to_f32(h));
      }
      Ah[mt] = ah; Al[mt] = al;
    }
#pragma unroll
    for (int nt = 0; nt < 4; ++nt) {
      const int px  = nt * 16 + r;
      const int csw = kk ^ ((px & 7) << 3);
      Bh[nt] = *reinterpret_cast<const short8*>(xthi + px * XROW + csw);
      Bl[nt] = *reinterpret_cast<const short8*>(xtlo + px * XROW + csw);
    }
#pragma unroll
    for (int mt = 0; mt < 4; ++mt)
#pragma unroll
      for (int nt = 0; nt < 4; ++nt) {
        acc[mt][nt] = __builtin_amdgcn_mfma_f32_16x16x32_bf16(Ah[mt], Bh[nt], acc[mt][nt], 0, 0, 0);
        acc[mt][nt] = __builtin_amdgcn_mfma_f32_16x16x32_bf16(Ah[mt], Bl[nt], acc[mt][nt], 0, 0, 0);
        acc[mt][nt] = __builtin_amdgcn_mfma_f32_16x16x32_bf16(Al[mt], Bh[nt], acc[mt][nt], 0, 0, 0);
      }
  }

  // ---- epilogue: lane holds pixel p0+nt*16+r, head n=half*4+mt, d=quad*4+reg
#pragma unroll
  for (int mt = 0; mt < 4; ++mt) {
    const int n = half * 4 + mt;
    const f32x4 b4 = *reinterpret_cast<const f32x4*>(bias + mbase + mt * 16 + quad * 4);
#pragma unroll
    for (int nt = 0; nt < 4; ++nt) {
      const int p = p0 + nt * 16 + r;
      const size_t off = ((size_t)((b * NHn + n) * HWn + p)) * DHn + quad * 4;
      f32x4 val = acc[mt][nt] + b4;
      if (mat == 0) {
        u16x4 hi4, lo4;
#pragma unroll
        for (int j = 0; j < 4; ++j) {
          const unsigned short hb = f32_to_bf16_rne(val[j]);
          hi4[j] = hb;
          lo4[j] = f32_to_bf16_rne(val[j] - bf16_to_f32(hb));
        }
        *reinterpret_cast<u16x4*>(qo + off)          = hi4;
        *reinterpret_cast<u16x4*>(qo + QPLANE + off) = lo4;
      } else {
        unsigned short* y = (mat == 1) ? kbf : vbf;
        u16x4 pkv;
        pkv[0] = f32_to_bf16_rne(val[0]); pkv[1] = f32_to_bf16_rne(val[1]);
        pkv[2] = f32_to_bf16_rne(val[2]); pkv[3] = f32_to_bf16_rne(val[3]);
        *reinterpret_cast<u16x4*>(y + off) = pkv;
      }
    }
  }
}

// ---------------------------------------------------------------------------
// Kernel 2: SASA attention via MFMA (round-2 known-good; natural block order
// — the XCD remap experiment regressed and is reverted).
// One block = (batch, head, 16x16 tile), 4 waves.
// grid (4, 4, 32), block 256.  LDS 44 KB static.
// ---------------------------------------------------------------------------
__global__ __launch_bounds__(256)
void sasa_attn(const unsigned short* __restrict__ qhl,
               const unsigned short* __restrict__ kbf,
               const unsigned short* __restrict__ vbf,
               const float* __restrict__ bk_, const float* __restrict__ bv_,
               const float* __restrict__ pos_h, const float* __restrict__ pos_w,
               float* __restrict__ out)
{
  __shared__ __align__(16) unsigned short ksm[HR * HC * KP];   // 25,344 B
  __shared__ __align__(16) unsigned       vsm[HR * DHn * VW];  // 19,712 B

  const int z  = blockIdx.z;
  const int b  = z >> 3;
  const int n  = z & 7;
  const int h0 = blockIdx.y * TS;
  const int w0 = blockIdx.x * TS;
  const int tid  = threadIdx.x;
  const int lane = tid & 63;
  const int wv   = tid >> 6;
  const int r    = lane & 15;
  const int quad = lane >> 4;
  const int cbase = n * DHn;

  const unsigned short* kb = kbf + ((size_t)(b * NHn + n) * HWn) * DHn;
  const unsigned short* vb = vbf + ((size_t)(b * NHn + n) * HWn) * DHn;
  const size_t qbase = ((size_t)(b * NHn + n) * HWn) * DHn;
  const unsigned short* qhp = qhl + qbase;
  const unsigned short* qlp = qhl + QPLANE + qbase;

  // bias halves as packed bf16 (for OOB halo pixels)
  u16x8 kb0, kb1, vb0, vb1;
#pragma unroll
  for (int j = 0; j < 8; ++j) {
    kb0[j] = f32_to_bf16_rne(bk_[cbase + j]);
    kb1[j] = f32_to_bf16_rne(bk_[cbase + 8 + j]);
    vb0[j] = f32_to_bf16_rne(bv_[cbase + j]);
    vb1[j] = f32_to_bf16_rne(bv_[cbase + 8 + j]);
  }

  // ---- stage K halo: 22x24 pixels x 2 halves (16 B each), [hh][ww][16+8pad]
  for (int c = tid; c < HR * HC * 2; c += 256) {
    const int pix  = c >> 1;
    const int half = c & 1;
    const int hh = pix / HC;
    const int ww = pix - hh * HC;
    const int gh = h0 + hh - PADn;
    const int gw = w0 + ww - PADn;
    const bool inb = (gh >= 0) && (gh < Hn) && (gw >= 0) && (gw < Wn);
    u16x8 kd;
    if (inb) kd = *reinterpret_cast<const u16x8*>(kb + ((size_t)(gh * Wn + gw)) * DHn + half * 8);
    else     kd = half ? kb1 : kb0;
    *reinterpret_cast<u16x8*>(ksm + pix * KP + half * 8) = kd;
  }

  // ---- stage V halo TRANSPOSED: vsm[hh][d][ww-pair] as u32 (lo=even ww)
  for (int pp = tid; pp < HR * (HC / 2); pp += 256) {
    const int hh = pp / (HC / 2);
    const int wp = pp - hh * (HC / 2);
    const int gh = h0 + hh - PADn;
    u16x8 a0, a1, c0, c1;
    {
      const int gw = w0 + 2 * wp - PADn;
      const bool inb = (gh >= 0) && (gh < Hn) && (gw >= 0) && (gw < Wn);
      if (inb) {
        const size_t src = ((size_t)(gh * Wn + gw)) * DHn;
        a0 = *reinterpret_cast<const u16x8*>(vb + src);
        a1 = *reinterpret_cast<const u16x8*>(vb + src + 8);
      } else { a0 = vb0; a1 = vb1; }
    }
    {
      const int gw = w0 + 2 * wp + 1 - PADn;
      const bool inb = (gh >= 0) && (gh < Hn) && (gw >= 0) && (gw < Wn);
      if (inb) {
        const size_t src = ((size_t)(gh * Wn + gw)) * DHn;
        c0 = *reinterpret_cast<const u16x8*>(vb + src);
        c1 = *reinterpret_cast<const u16x8*>(vb + src + 8);
      } else { c0 = vb0; c1 = vb1; }
    }
    unsigned* dst = vsm + (hh * DHn) * VW + wp;
#pragma unroll
    for (int d = 0; d < 8; ++d)
      dst[d * VW] = (unsigned)(unsigned short)a0[d] | ((unsigned)(unsigned short)c0[d] << 16);
#pragma unroll
    for (int d = 0; d < 8; ++d)
      dst[(8 + d) * VW] = (unsigned)(unsigned short)a1[d] | ((unsigned)(unsigned short)c1[d] << 16);
  }

  // ---- per-lane static pos_w + band-validity masks
  float ph[7];
#pragma unroll
  for (int i = 0; i < 7; ++i) ph[i] = pos_h[n * Kn + i];
  f32x4 pw4[2];
#pragma unroll
  for (int win = 0; win < 2; ++win) {
#pragma unroll
    for (int reg = 0; reg < 4; ++reg) {
      const int ww = win * 8 + 4 * quad + reg;
      const int j  = ww - r;
      const bool valid = (j >= 0) && (j < 7) && (win == 0 || ww >= 16);
      const int jc = j < 0 ? 0 : (j > 6 ? 6 : j);
      const float pv = pos_w[n * Kn + jc];
      pw4[win][reg] = valid ? pv : -1e30f;
    }
  }

  __syncthreads();

  const f32x4 zero4 = {};
  for (int hl = 0; hl < 4; ++hl) {
    const int h = wv * 4 + hl;

    // ---- QK^T B-fragment: q bf16, slot s<16 -> qh[d=s], s>=16 -> ql[d=s-16]
    const int pix = (h0 + h) * Wn + (w0 + r);
    const unsigned short* qsel = (quad < 2) ? qhp : qlp;
    const short8 qf = *reinterpret_cast<const short8*>(qsel + (size_t)pix * DHn + (quad & 1) * 8);

    // ---- logits: 14 MFMAs (7 i x 2 windows)
    f32x4 L[14];
#pragma unroll
    for (int i = 0; i < 7; ++i) {
#pragma unroll
      for (int win = 0; win < 2; ++win) {
        const short8 kf = *reinterpret_cast<const short8*>(
            ksm + ((h + i) * HC + win * 8 + r) * KP + (quad & 1) * 8);
        f32x4 d = __builtin_amdgcn_mfma_f32_16x16x32_bf16(kf, qf, zero4, 0, 0, 0);
        d = d + pw4[win];
        d = d + (f32x4)ph[i];
        L[i * 2 + win] = d;
      }
    }

    // ---- softmax over this pixel's 49 valid slots
    f32x4 M4 = L[0];
#pragma unroll
    for (int t = 1; t < 14; ++t) M4 = max4(M4, L[t]);
    float m = fmaxf(fmaxf(M4[0], M4[1]), fmaxf(M4[2], M4[3]));
    m = fmaxf(m, __shfl_xor(m, 16, 64));
    m = fmaxf(m, __shfl_xor(m, 32, 64));

    f32x4 S4 = {};
#pragma unroll
    for (int t = 0; t < 14; ++t) {
      f32x4 e;
      e[0] = __expf(L[t][0] - m);
      e[1] = __expf(L[t][1] - m);
      e[2] = __expf(L[t][2] - m);
      e[3] = __expf(L[t][3] - m);
      L[t] = e;
      S4 += e;
    }
    float s = (S4[0] + S4[1]) + (S4[2] + S4[3]);
    s += __shfl_xor(s, 16, 64);
    s += __shfl_xor(s, 32, 64);
    const float inv = 1.0f / s;

    // ---- PV: 7 MFMAs, weights in-lane (D-fragment == A-fragment layout)
    f32x4 oA = {}, oB = {};
#pragma unroll
    for (int i = 0; i < 7; ++i) {
      const f32x4 e0 = L[2 * i]     * (f32x4)inv;
      const f32x4 e1 = L[2 * i + 1] * (f32x4)inv;
      UVcast A;
      A.u[0] = pk_bf16(e0[0], e0[1]);
      A.u[1] = pk_bf16(e0[2], e0[3]);
      A.u[2] = pk_bf16(e1[0], e1[1]);
      A.u[3] = pk_bf16(e1[2], e1[3]);

      const unsigned* vp = vsm + ((h + i) * DHn + r) * VW + 2 * quad;
      const uint2 v0 = *reinterpret_cast<const uint2*>(vp);
      const uint2 v1 = *reinterpret_cast<const uint2*>(vp + 4);
      UVcast Bv;
      Bv.u[0] = v0.x; Bv.u[1] = v0.y; Bv.u[2] = v1.x; Bv.u[3] = v1.y;

      f32x4& acc = (i & 1) ? oB : oA;
      acc = __builtin_amdgcn_mfma_f32_16x16x32_bf16(A.s, Bv.s, acc, 0, 0, 0);
    }
    const f32x4 O = oA + oB;

    // ---- store: D[row=w=4q+reg][col=d=r] -> f32x4 contiguous in w
    float* op = out + ((size_t)(b * Cn + cbase + r)) * HWn + (h0 + h) * Wn + w0 + 4 * quad;
    *reinterpret_cast<f32x4*>(op) = O;
  }
}

// ---------------------------------------------------------------------------
extern "C" void kernel_launch(void* const* d_in, const int* in_sizes, int n_in,
                              void* d_out, int out_size, void* d_ws, size_t ws_size,
                              hipStream_t stream) {
  const float* x     = (const float*)d_in[0];
  const float* wq    = (const float*)d_in[1];
  const float* bq    = (const float*)d_in[2];
  const float* wk    = (const float*)d_in[3];
  const float* bk    = (const float*)d_in[4];
  const float* wv    = (const float*)d_in[5];
  const float* bv    = (const float*)d_in[6];
  const float* pos_h = (const float*)d_in[7];
  const float* pos_w = (const float*)d_in[8];
  float* out = (float*)d_out;

  const size_t tensor_elems = (size_t)Bn * Cn * HWn;          // 2,097,152
  unsigned short* qhl = (unsigned short*)d_ws;                // 8 MiB (hi+lo planes)
  unsigned short* kbf = qhl + 2 * tensor_elems;               // 4 MiB
  unsigned short* vbf = kbf + tensor_elems;                   // 4 MiB

  dim3 gq(HWn / SP, 1, Bn);              // (64, 1, 4)
  qkv_fused<<<gq, 512, 0, stream>>>(x, wq, wk, wv, bq, bk, bv, qhl, kbf, vbf);

  dim3 g2(Wn / TS, Hn / TS, Bn * NHn);   // (4, 4, 32)
  sasa_attn<<<g2, 256, 0, stream>>>(qhl, kbf, vbf, bk, bv, pos_h, pos_w, out);
}